// Round 1
// baseline (5801.950 us; speedup 1.0000x reference)
//
#include <hip/hip_runtime.h>
#include <hip/hip_bf16.h>
#include <math.h>

#define TT 64
#define FF 32
#define HH 64
#define G4 256   // 4*H
#define GG1 64
#define GG2 32

__device__ __forceinline__ float sigm(float v){ return 1.0f/(1.0f+expf(-v)); }

// ---------------------------------------------------------------------------
// Fused 2-layer LSTM over the full sequence. Block = 256 threads = gate rows.
// Each block processes 2 nodes; thread j keeps weight row j of all 4 weight
// matrices in registers (224 VGPRs) and reuses them across the 64 timesteps.
// h-state lives in LDS (broadcast reads); c-state lives in registers of the
// combine threads (j<128). Writes only the final layer-2 hidden state.
// ---------------------------------------------------------------------------
__global__ __launch_bounds__(256, 2) void lstm_fused(
    const float* __restrict__ x,
    const float* __restrict__ Wih0, const float* __restrict__ Whh0,
    const float* __restrict__ bih0, const float* __restrict__ bhh0,
    const float* __restrict__ Wih1, const float* __restrict__ Whh1,
    const float* __restrict__ bih1, const float* __restrict__ bhh1,
    float* __restrict__ hout, int n)
{
  const int j  = threadIdx.x;            // gate row 0..255
  const int nA = blockIdx.x * 2;
  const int nB = nA + 1;
  const bool hasB = (nB < n);

  // weight rows -> registers
  float wih0[FF], whh0[HH], wih1[HH], whh1[HH];
#pragma unroll
  for (int k = 0; k < FF; k += 4) *(float4*)&wih0[k] = *(const float4*)&Wih0[j*FF + k];
#pragma unroll
  for (int k = 0; k < HH; k += 4) *(float4*)&whh0[k] = *(const float4*)&Whh0[j*HH + k];
#pragma unroll
  for (int k = 0; k < HH; k += 4) *(float4*)&wih1[k] = *(const float4*)&Wih1[j*HH + k];
#pragma unroll
  for (int k = 0; k < HH; k += 4) *(float4*)&whh1[k] = *(const float4*)&Whh1[j*HH + k];
  const float b0 = bih0[j] + bhh0[j];
  const float b1 = bih1[j] + bhh1[j];

  __shared__ float xs [2][FF];
  __shared__ float h0s[2][HH];
  __shared__ float h1s[2][HH];
  __shared__ float gs [2][G4];

  if (j < 2*HH) { (&h0s[0][0])[j] = 0.0f; (&h1s[0][0])[j] = 0.0f; }
  float c0 = 0.0f, c1 = 0.0f;   // element (j&63) of node (j>>6), valid for j<128

  const float* xA = x + (size_t)nA * TT * FF;
  const float* xB = x + (size_t)nB * TT * FF;

  for (int t = 0; t < TT; ++t) {
    __syncthreads();
    if (j < FF)          xs[0][j]      = xA[t*FF + j];
    else if (j < 2*FF)   xs[1][j - FF] = hasB ? xB[t*FF + (j - FF)] : 0.0f;
    __syncthreads();

    // ---- layer 0 gates: a = b0 + x.wih0_row + h0.whh0_row ----
    float a0 = b0, a1 = b0;
#pragma unroll
    for (int k = 0; k < FF; ++k) {
      a0 = fmaf(xs[0][k], wih0[k], a0);
      a1 = fmaf(xs[1][k], wih0[k], a1);
    }
#pragma unroll
    for (int k = 0; k < HH; ++k) {
      a0 = fmaf(h0s[0][k], whh0[k], a0);
      a1 = fmaf(h0s[1][k], whh0[k], a1);
    }
    gs[0][j] = a0; gs[1][j] = a1;
    __syncthreads();

    if (j < 2*HH) {
      const int nd = j >> 6, m = j & 63;
      const float gi = gs[nd][m], gf = gs[nd][m+64], gg = gs[nd][m+128], go = gs[nd][m+192];
      c0 = sigm(gf)*c0 + sigm(gi)*tanhf(gg);
      h0s[nd][m] = sigm(go)*tanhf(c0);
    }
    __syncthreads();

    // ---- layer 1 gates: d = b1 + h0_new.wih1_row + h1.whh1_row ----
    float d0 = b1, d1 = b1;
#pragma unroll
    for (int k = 0; k < HH; ++k) {
      d0 = fmaf(h0s[0][k], wih1[k], d0);
      d1 = fmaf(h0s[1][k], wih1[k], d1);
    }
#pragma unroll
    for (int k = 0; k < HH; ++k) {
      d0 = fmaf(h1s[0][k], whh1[k], d0);
      d1 = fmaf(h1s[1][k], whh1[k], d1);
    }
    gs[0][j] = d0; gs[1][j] = d1;
    __syncthreads();

    if (j < 2*HH) {
      const int nd = j >> 6, m = j & 63;
      const float gi = gs[nd][m], gf = gs[nd][m+64], gg = gs[nd][m+128], go = gs[nd][m+192];
      c1 = sigm(gf)*c1 + sigm(gi)*tanhf(gg);
      h1s[nd][m] = sigm(go)*tanhf(c1);
    }
  }
  __syncthreads();
  if (j < 2*HH) {
    const int nd = j >> 6, m = j & 63;
    const int node = nA + nd;
    if (node < n) hout[(size_t)node*HH + m] = h1s[nd][m];
  }
}

// ---------------------------------------------------------------------------
// GCN support kernels
// ---------------------------------------------------------------------------
__global__ void k_count(const int* __restrict__ dst, int E, int* __restrict__ cnt)
{
  int e = blockIdx.x * blockDim.x + threadIdx.x;
  if (e < E) atomicAdd(&cnt[dst[e]], 1);
}

// single-block exclusive scan over cnt -> offs (also cursor copy + dinv)
__global__ void k_scan_build(const int* __restrict__ cnt, int n,
                             int* __restrict__ offs, int* __restrict__ cursor,
                             float* __restrict__ dinv)
{
  __shared__ int part[1024];
  const int tid = threadIdx.x;
  const int per = (n + 1023) >> 10;
  const int base = tid * per;
  int s = 0;
  for (int i = 0; i < per; ++i) { int idx = base + i; if (idx < n) s += cnt[idx]; }
  part[tid] = s;
  __syncthreads();
  for (int off = 1; off < 1024; off <<= 1) {
    int v = 0;
    if (tid >= off) v = part[tid - off];
    __syncthreads();
    part[tid] += v;
    __syncthreads();
  }
  int run = part[tid] - s;   // exclusive prefix of this thread's chunk
  for (int i = 0; i < per; ++i) {
    int idx = base + i;
    if (idx < n) {
      offs[idx] = run; cursor[idx] = run;
      int c = cnt[idx];
      dinv[idx] = 1.0f / sqrtf((float)(c + 1));   // +1 self-loop
      run += c;
    }
  }
}

__global__ void k_fill(const int* __restrict__ src, const int* __restrict__ dst,
                       int E, int* __restrict__ cursor, int* __restrict__ csr)
{
  int e = blockIdx.x * blockDim.x + threadIdx.x;
  if (e < E) {
    int d = dst[e];
    int pos = atomicAdd(&cursor[d], 1);
    csr[pos] = src[e];
  }
}

// out[n,M] = A[n,K] @ W[K,M]
template <int K, int M>
__global__ void k_xw(const float* __restrict__ A, const float* __restrict__ W,
                     float* __restrict__ out, int n)
{
  int idx = blockIdx.x * blockDim.x + threadIdx.x;
  int row = idx / M, col = idx % M;
  if (row >= n) return;
  const float* a = A + (size_t)row * K;
  float acc = 0.0f;
#pragma unroll
  for (int k = 0; k < K; ++k) acc = fmaf(a[k], W[k*M + col], acc);
  out[(size_t)row*M + col] = acc;
}

// CSR gather-aggregate + bias + relu. FD lanes per node.
template <int FD>
__global__ void k_agg(const float* __restrict__ xw, const int* __restrict__ offs,
                      const int* __restrict__ cnt, const int* __restrict__ csr,
                      const float* __restrict__ dinv, const float* __restrict__ b,
                      float* __restrict__ out, int n)
{
  int gidx = blockIdx.x * blockDim.x + threadIdx.x;
  int node = gidx / FD, lane = gidx % FD;
  if (node >= n) return;
  const float di = dinv[node];
  float acc = xw[(size_t)node*FD + lane] * di * di;     // self loop
  const int s0 = offs[node], e0 = s0 + cnt[node];
  for (int p = s0; p < e0; ++p) {
    int s = csr[p];
    acc = fmaf(xw[(size_t)s*FD + lane], dinv[s] * di, acc);
  }
  out[(size_t)node*FD + lane] = fmaxf(acc + b[lane], 0.0f);
}

__global__ void k_fc(const float* __restrict__ g2, const int* __restrict__ sid,
                     const float* __restrict__ fcW, const float* __restrict__ fcb,
                     float* __restrict__ out, int n)
{
  int i = blockIdx.x * blockDim.x + threadIdx.x;
  if (i >= n) return;
  const float* row = g2 + (size_t)sid[i] * GG2;
  float acc = fcb[0];
#pragma unroll
  for (int f = 0; f < GG2; ++f) acc = fmaf(row[f], fcW[f], acc);
  out[i] = acc;
}

// ---------------------------------------------------------------------------
extern "C" void kernel_launch(void* const* d_in, const int* in_sizes, int n_in,
                              void* d_out, int out_size, void* d_ws, size_t ws_size,
                              hipStream_t stream)
{
  const float* x    = (const float*)d_in[0];
  const int*   sid  = (const int*)  d_in[1];
  const int*   eidx = (const int*)  d_in[2];
  const float* Wih0 = (const float*)d_in[3];
  const float* Whh0 = (const float*)d_in[4];
  const float* bih0 = (const float*)d_in[5];
  const float* bhh0 = (const float*)d_in[6];
  const float* Wih1 = (const float*)d_in[7];
  const float* Whh1 = (const float*)d_in[8];
  const float* bih1 = (const float*)d_in[9];
  const float* bhh1 = (const float*)d_in[10];
  const float* g1W  = (const float*)d_in[11];
  const float* g1b  = (const float*)d_in[12];
  const float* g2W  = (const float*)d_in[13];
  const float* g2b  = (const float*)d_in[14];
  const float* fcW  = (const float*)d_in[15];
  const float* fcb  = (const float*)d_in[16];

  const int n = in_sizes[1];        // N nodes
  const int E = in_sizes[2] / 2;    // edges
  float* out = (float*)d_out;

  // workspace carve-up (~23.4 MB)
  char* w = (char*)d_ws;
  auto carve = [&](size_t bytes) -> void* {
    void* p = (void*)w; w += (bytes + 255) & ~(size_t)255; return p;
  };
  float* hfin   = (float*)carve((size_t)n * HH * 4);
  int*   cnt    = (int*)  carve((size_t)n * 4);
  int*   offs   = (int*)  carve((size_t)n * 4);
  int*   cursor = (int*)  carve((size_t)n * 4);
  float* dinv   = (float*)carve((size_t)n * 4);
  int*   csr    = (int*)  carve((size_t)E * 4);
  float* xw1    = (float*)carve((size_t)n * GG1 * 4);
  float* g1     = (float*)carve((size_t)n * GG1 * 4);
  float* xw2    = (float*)carve((size_t)n * GG2 * 4);
  float* g2     = (float*)carve((size_t)n * GG2 * 4);

  const int* src = eidx;
  const int* dst = eidx + E;

  // 1) fused 2-layer LSTM -> final hidden state
  lstm_fused<<<(n + 1) / 2, 256, 0, stream>>>(x, Wih0, Whh0, bih0, bhh0,
                                              Wih1, Whh1, bih1, bhh1, hfin, n);

  // 2) build CSR by dst (+ degree-norm terms)
  hipMemsetAsync(cnt, 0, (size_t)n * 4, stream);
  k_count<<<(E + 255) / 256, 256, 0, stream>>>(dst, E, cnt);
  k_scan_build<<<1, 1024, 0, stream>>>(cnt, n, offs, cursor, dinv);
  k_fill<<<(E + 255) / 256, 256, 0, stream>>>(src, dst, E, cursor, csr);

  // 3) GCN layer 1: xw -> aggregate -> +b, relu
  k_xw<HH, GG1><<<((size_t)n * GG1 + 255) / 256, 256, 0, stream>>>(hfin, g1W, xw1, n);
  k_agg<GG1><<<((size_t)n * GG1 + 255) / 256, 256, 0, stream>>>(xw1, offs, cnt, csr, dinv, g1b, g1, n);

  // 4) GCN layer 2
  k_xw<GG1, GG2><<<((size_t)n * GG2 + 255) / 256, 256, 0, stream>>>(g1, g2W, xw2, n);
  k_agg<GG2><<<((size_t)n * GG2 + 255) / 256, 256, 0, stream>>>(xw2, offs, cnt, csr, dinv, g2b, g2, n);

  // 5) gather by stock_ids + fc
  k_fc<<<(n + 255) / 256, 256, 0, stream>>>(g2, sid, fcW, fcb, out, n);
}